// Round 4
// baseline (317.715 us; speedup 1.0000x reference)
//
#include <hip/hip_runtime.h>
#include <hip/hip_bf16.h>

// ---- problem constants ----
constexpr int N0 = 400000, N1 = 75000, N2 = 15000;
constexpr int E1 = 1200000, E2 = 240000;
constexpr int F_IN = 64, NC = 40;
constexpr float NEG_SLOPE = 0.2f;

// dst-range binning: one block per range in the aggregate kernels.
// Each range has 8 XCD-sliced append cells so bin writes stay XCD-local.
constexpr int R1 = 37;                      // dst nodes per range, layer 1
constexpr int NR1 = (N1 + R1 - 1) / R1;     // 2028
constexpr int CAP1 = 160;                   // per-cell capacity; mean 74, sigma 8.6
constexpr int R2 = 15;                      // dst nodes per range, layer 2
constexpr int NR2 = (N2 + R2 - 1) / R2;     // 1000
constexpr int CAP2 = 96;                    // mean 30, sigma 5.5

constexpr int B_E1 = (E1 + 255) / 256;      // 4688
constexpr int B_E2 = (E2 + 255) / 256;      // 938
constexpr int B_PS = (N0 + 255) / 256;      // 1563
constexpr int B_PD = (N1 + 255) / 256;      // 293

__device__ __forceinline__ float leaky(float v) { return v > 0.f ? v : NEG_SLOPE * v; }

// ============ K1: bin(E1) + bin(E2) + projS(N0) + projD(N1) ============
__global__ __launch_bounds__(256) void k1_kernel(
    const float* __restrict__ x,
    const float* __restrict__ W1s, const float* __restrict__ W1d,
    const float* __restrict__ att1s, const float* __restrict__ att1d,
    const int* __restrict__ e1s, const int* __restrict__ e1d,
    const int* __restrict__ e2s, const int* __restrict__ e2d,
    float* __restrict__ hs1, float* __restrict__ a_s1, float* __restrict__ a_d1,
    int* __restrict__ cnt1, unsigned* __restrict__ bin1,
    int* __restrict__ cnt2, unsigned* __restrict__ bin2)
{
    int bid = blockIdx.x;
    const int slice = blockIdx.x & 7;       // ~XCD id under round-robin dispatch (perf-only)
    if (bid < B_E1) {
        int e = bid * 256 + threadIdx.x;
        if (e < E1) {
            int s = e1s[e], d = e1d[e];
            if (s != d) {                   // remove_self_loops
                int r = d / R1, nd = d - r * R1;
                int cell = r * 8 + slice;
                int pos = atomicAdd(&cnt1[cell], 1);
                if (pos < CAP1) bin1[(size_t)cell * CAP1 + pos] = (unsigned)s | ((unsigned)nd << 19);
            }
        }
        return;
    }
    bid -= B_E1;
    if (bid < B_E2) {
        int e = bid * 256 + threadIdx.x;
        if (e < E2) {
            int s = e2s[e], d = e2d[e];
            if (s != d) {
                int r = d / R2, nd = d - r * R2;
                int cell = r * 8 + slice;
                int pos = atomicAdd(&cnt2[cell], 1);
                if (pos < CAP2) bin2[(size_t)cell * CAP2 + pos] = (unsigned)s | ((unsigned)nd << 17);
            }
        }
        return;
    }
    bid -= B_E2;
    if (bid < B_PS) {
        // ---- projS: hs1[node][16] = x[node] @ W1s ; a_s1[node][2] ----
        int node = bid * 256 + threadIdx.x;
        if (node >= N0) return;
        const float4* xp = (const float4*)(x + (size_t)node * F_IN);
        float ss[16];
        #pragma unroll
        for (int c = 0; c < 16; ++c) ss[c] = 0.f;
        #pragma unroll
        for (int j = 0; j < 16; ++j) {
            float4 t = xp[j];
            float xk[4] = {t.x, t.y, t.z, t.w};
            #pragma unroll
            for (int kk = 0; kk < 4; ++kk)
                #pragma unroll
                for (int c = 0; c < 16; ++c)
                    ss[c] = fmaf(xk[kk], W1s[(4 * j + kk) * 16 + c], ss[c]);
        }
        float4* hp = (float4*)(hs1 + (size_t)node * 16);
        hp[0] = make_float4(ss[0], ss[1], ss[2], ss[3]);
        hp[1] = make_float4(ss[4], ss[5], ss[6], ss[7]);
        hp[2] = make_float4(ss[8], ss[9], ss[10], ss[11]);
        hp[3] = make_float4(ss[12], ss[13], ss[14], ss[15]);
        float a0 = 0.f, a1 = 0.f;
        #pragma unroll
        for (int c = 0; c < 8; ++c) {
            a0 = fmaf(ss[c], att1s[c], a0);
            a1 = fmaf(ss[8 + c], att1s[8 + c], a1);
        }
        ((float2*)a_s1)[node] = make_float2(a0, a1);
        return;
    }
    bid -= B_PS;
    {
        // ---- projD: a_d1[node][2] from x[node] @ W1d ----
        int node = bid * 256 + threadIdx.x;
        if (node >= N1) return;
        const float4* xp = (const float4*)(x + (size_t)node * F_IN);
        float sd[16];
        #pragma unroll
        for (int c = 0; c < 16; ++c) sd[c] = 0.f;
        #pragma unroll
        for (int j = 0; j < 16; ++j) {
            float4 t = xp[j];
            float xk[4] = {t.x, t.y, t.z, t.w};
            #pragma unroll
            for (int kk = 0; kk < 4; ++kk)
                #pragma unroll
                for (int c = 0; c < 16; ++c)
                    sd[c] = fmaf(xk[kk], W1d[(4 * j + kk) * 16 + c], sd[c]);
        }
        float a0 = 0.f, a1 = 0.f;
        #pragma unroll
        for (int c = 0; c < 8; ++c) {
            a0 = fmaf(sd[c], att1d[c], a0);
            a1 = fmaf(sd[8 + c], att1d[8 + c], a1);
        }
        ((float2*)a_d1)[node] = make_float2(a0, a1);
    }
}

// ============ K2: layer-1 edge-major aggregate + fused proj2 ============
// one block per dst-range; LDS acc; then ELU + (16x40 dot) -> hs2, a_s2, a_d2
__global__ __launch_bounds__(256) void k2_kernel(
    const int* __restrict__ cnt1, const unsigned* __restrict__ bin1,
    const float* __restrict__ a_s1, const float* __restrict__ a_d1,
    const float* __restrict__ hs1, const float* __restrict__ b1,
    const float* __restrict__ W2s, const float* __restrict__ W2d,
    const float* __restrict__ att2s, const float* __restrict__ att2d,
    float* __restrict__ hs2, float* __restrict__ a_s2, float* __restrict__ a_d2)
{
    __shared__ float acc[R1 * 16];     // per-node weighted sums, later ELU(h1)
    __shared__ float den[R1 * 2];      // per-(node,head) denominators
    __shared__ float adl[R1 * 2];      // a_d1 for range
    __shared__ float w2s[16 * 40], w2d[16 * 40];
    __shared__ float as2l[R1], ad2l[R1];

    const int r = blockIdx.x, tid = threadIdx.x;
    const int d0 = r * R1;
    const int nN = min(R1, N1 - d0);

    for (int j = tid; j < 640; j += 256) { w2s[j] = W2s[j]; w2d[j] = W2d[j]; }
    // self-loop weight + a_d cache, per (node,head)
    for (int i = tid; i < nN * 2; i += 256) {
        int d = d0 + (i >> 1), h = i & 1;
        float ad = a_d1[(size_t)d * 2 + h];
        adl[i] = ad;
        den[i] = __expf(leaky(a_s1[(size_t)d * 2 + h] + ad));
    }
    for (int i = tid; i < nN; i += 256) { as2l[i] = 0.f; ad2l[i] = 0.f; }
    __syncthreads();
    // acc init with self-loop contribution
    for (int i = tid; i < nN * 16; i += 256) {
        int n = i >> 4, c = i & 15, h = c >> 3;
        acc[i] = den[n * 2 + h] * hs1[(size_t)(d0 + n) * 16 + c];
    }
    __syncthreads();

    // edge-major accumulation: 16 groups of 16 lanes; group = one edge
    const int g = tid >> 4, c = tid & 15, h = c >> 3;
    for (int seg = 0; seg < 8; ++seg) {
        const int cell = r * 8 + seg;
        const int ne = min(cnt1[cell], CAP1);
        const unsigned* bp = bin1 + (size_t)cell * CAP1;
        unsigned p = (g < ne) ? bp[g] : 0u;
        for (int j = g; j < ne; j += 16) {
            unsigned pn = (j + 16 < ne) ? bp[j + 16] : 0u;
            int s = p & 0x7FFFF, nd = p >> 19;
            float w = __expf(leaky(a_s1[(size_t)s * 2 + h] + adl[nd * 2 + h]));
            float hv = hs1[(size_t)s * 16 + c];
            atomicAdd(&acc[nd * 16 + c], w * hv);
            if ((c & 7) == 0) atomicAdd(&den[nd * 2 + h], w);
            p = pn;
        }
    }
    __syncthreads();
    // normalize + bias + ELU, in place
    for (int i = tid; i < nN * 16; i += 256) {
        int n = i >> 4, cc = i & 15, h2 = cc >> 3;
        float v = acc[i] / den[n * 2 + h2] + b1[cc];
        acc[i] = v > 0.f ? v : (__expf(v) - 1.f);
    }
    __syncthreads();
    // fused proj2: hs2[d][cc] = acc[n][:] @ W2s[:,cc] ; a_s2 ; a_d2 (d < N2)
    for (int i = tid; i < nN * 40; i += 256) {
        int n = i / 40, cc = i - n * 40;
        int d = d0 + n;
        float s = 0.f;
        #pragma unroll
        for (int k = 0; k < 16; ++k) s = fmaf(acc[n * 16 + k], w2s[k * 40 + cc], s);
        hs2[(size_t)d * 40 + cc] = s;
        atomicAdd(&as2l[n], s * att2s[cc]);
        if (d < N2) {
            float sd = 0.f;
            #pragma unroll
            for (int k = 0; k < 16; ++k) sd = fmaf(acc[n * 16 + k], w2d[k * 40 + cc], sd);
            atomicAdd(&ad2l[n], sd * att2d[cc]);
        }
    }
    __syncthreads();
    for (int i = tid; i < nN; i += 256) {
        a_s2[d0 + i] = as2l[i];
        if (d0 + i < N2) a_d2[d0 + i] = ad2l[i];
    }
}

// ============ K4: layer-2 edge-major aggregate + fused log_softmax ============
__global__ __launch_bounds__(256) void k4_kernel(
    const int* __restrict__ cnt2, const unsigned* __restrict__ bin2,
    const float* __restrict__ a_s2, const float* __restrict__ a_d2,
    const float* __restrict__ hs2, const float* __restrict__ b2,
    float* __restrict__ out)
{
    __shared__ float acc[R2 * 40];
    __shared__ float den[R2];
    __shared__ float adl[R2];

    const int r = blockIdx.x, tid = threadIdx.x;
    const int d0 = r * R2;
    const int nN = min(R2, N2 - d0);

    for (int i = tid; i < nN; i += 256) {
        int d = d0 + i;
        float ad = a_d2[d];
        adl[i] = ad;
        den[i] = __expf(leaky(a_s2[d] + ad));
    }
    __syncthreads();
    for (int i = tid; i < nN * 40; i += 256) {
        int n = i / 40, cc = i - n * 40;
        acc[i] = den[n] * hs2[(size_t)(d0 + n) * 40 + cc];
    }
    __syncthreads();

    // one edge per wave iteration (lanes 0..39 carry channels)
    const int wv = tid >> 6, lane = tid & 63;
    const bool act = lane < NC;
    for (int seg = 0; seg < 8; ++seg) {
        const int cell = r * 8 + seg;
        const int ne = min(cnt2[cell], CAP2);
        const unsigned* bp = bin2 + (size_t)cell * CAP2;
        unsigned p = (wv < ne) ? bp[wv] : 0u;
        for (int j = wv; j < ne; j += 4) {
            unsigned pn = (j + 4 < ne) ? bp[j + 4] : 0u;
            int s = p & 0x1FFFF, nd = p >> 17;
            float w = __expf(leaky(a_s2[s] + adl[nd]));
            if (act) atomicAdd(&acc[nd * 40 + lane], w * hs2[(size_t)s * 40 + lane]);
            if (lane == 0) atomicAdd(&den[nd], w);
            p = pn;
        }
    }
    __syncthreads();

    // finalize: one wave per node, log_softmax over 40 lanes
    for (int n = wv; n < nN; n += 4) {
        float v = act ? (acc[n * 40 + lane] / den[n] + b2[lane]) : 0.f;
        float vv = act ? v : -3.4e38f;
        #pragma unroll
        for (int k = 32; k >= 1; k >>= 1) vv = fmaxf(vv, __shfl_xor(vv, k));
        float ex = act ? __expf(v - vv) : 0.f;
        #pragma unroll
        for (int k = 32; k >= 1; k >>= 1) ex += __shfl_xor(ex, k);
        float lse = vv + logf(ex);
        if (act) out[(size_t)(d0 + n) * NC + lane] = v - lse;
    }
}

extern "C" void kernel_launch(void* const* d_in, const int* in_sizes, int n_in,
                              void* d_out, int out_size, void* d_ws, size_t ws_size,
                              hipStream_t stream) {
    const float* x      = (const float*)d_in[0];
    const int*   e1_src = (const int*)d_in[1];
    const int*   e1_dst = (const int*)d_in[2];
    const int*   e2_src = (const int*)d_in[3];
    const int*   e2_dst = (const int*)d_in[4];
    const float* W1s    = (const float*)d_in[5];
    const float* W1d    = (const float*)d_in[6];
    const float* att1s  = (const float*)d_in[7];
    const float* att1d  = (const float*)d_in[8];
    const float* b1     = (const float*)d_in[9];
    const float* W2s    = (const float*)d_in[10];
    const float* W2d    = (const float*)d_in[11];
    const float* att2s  = (const float*)d_in[12];
    const float* att2d  = (const float*)d_in[13];
    const float* b2     = (const float*)d_in[14];
    float* out = (float*)d_out;

    // ---- workspace layout (4-byte words) ----
    float* wsbase = (float*)d_ws;
    size_t o = 0;
    int*      cnt1 = (int*)(wsbase + o);      o += (size_t)NR1 * 8;
    int*      cnt2 = (int*)(wsbase + o);      o += (size_t)NR2 * 8;
    const size_t zeroWords = o;               // only counters need zeroing
    unsigned* bin1 = (unsigned*)(wsbase + o); o += (size_t)NR1 * 8 * CAP1;
    unsigned* bin2 = (unsigned*)(wsbase + o); o += (size_t)NR2 * 8 * CAP2;
    float* hs1  = wsbase + o; o += (size_t)N0 * 16;
    float* a_s1 = wsbase + o; o += (size_t)N0 * 2;
    float* a_d1 = wsbase + o; o += (size_t)N1 * 2;
    float* hs2  = wsbase + o; o += (size_t)N1 * 40;
    float* a_s2 = wsbase + o; o += (size_t)N1;
    float* a_d2 = wsbase + o; o += (size_t)N2;

    hipMemsetAsync(d_ws, 0, zeroWords * sizeof(float), stream);

    k1_kernel<<<B_E1 + B_E2 + B_PS + B_PD, 256, 0, stream>>>(
        x, W1s, W1d, att1s, att1d, e1_src, e1_dst, e2_src, e2_dst,
        hs1, a_s1, a_d1, cnt1, bin1, cnt2, bin2);

    k2_kernel<<<NR1, 256, 0, stream>>>(cnt1, bin1, a_s1, a_d1, hs1, b1,
                                       W2s, W2d, att2s, att2d, hs2, a_s2, a_d2);

    k4_kernel<<<NR2, 256, 0, stream>>>(cnt2, bin2, a_s2, a_d2, hs2, b2, out);
}

// Round 5
// 247.668 us; speedup vs baseline: 1.2828x; 1.2828x over previous
//
#include <hip/hip_runtime.h>
#include <hip/hip_bf16.h>

// ---- problem constants ----
constexpr int N0 = 400000, N1 = 75000, N2 = 15000;
constexpr int E1 = 1200000, E2 = 240000;
constexpr int NC = 40;
constexpr float NEG_SLOPE = 0.2f;

// ranges of 16 dst nodes; 8 XCD-sliced append cells per range, slice-major layout
constexpr int NRB1 = (N1 + 15) / 16;     // 4688
constexpr int NRB2 = (N2 + 15) / 16;     // 938
constexpr int CAPC = 80;                 // per-cell cap (mean ~34, 8 sigma head-room)
constexpr int MAXE = 512;                // per-block sorted-list cap (mean ~270, 15 sigma)

constexpr int B_E1 = (E1 + 255) / 256;   // 4688
constexpr int B_E2 = (E2 + 255) / 256;   // 938
constexpr int B_P  = (N0 + 255) / 256;   // 1563

__device__ __forceinline__ float leaky(float v) { return v > 0.f ? v : NEG_SLOPE * v; }

// RNE pack of two floats into a bf16x2 word (lo in low half, hi in high half)
__device__ __forceinline__ unsigned bf16pair(float lo, float hi) {
    unsigned a = __float_as_uint(lo), b = __float_as_uint(hi);
    a = (a + 0x7FFFu + ((a >> 16) & 1u)) >> 16;
    b = (b + 0x7FFFu + ((b >> 16) & 1u)) & 0xFFFF0000u;
    return a | b;
}
__device__ __forceinline__ float bfLo(unsigned w) { return __uint_as_float(w << 16); }
__device__ __forceinline__ float bfHi(unsigned w) { return __uint_as_float(w & 0xFFFF0000u); }

// ============ K1: bin(E1) + bin(E2) + proj(S and D fused) ============
// rec1[node] (16 words, 64B): w0..w7 = bf16x2 hs1 channels, w8/w9 = fp32 a_s (head0/1)
__global__ __launch_bounds__(256) void k1_kernel(
    const float* __restrict__ x,
    const float* __restrict__ W1s, const float* __restrict__ W1d,
    const float* __restrict__ att1s, const float* __restrict__ att1d,
    const int* __restrict__ e1s, const int* __restrict__ e1d,
    const int* __restrict__ e2s, const int* __restrict__ e2d,
    unsigned* __restrict__ rec1, float* __restrict__ a_d1,
    int* __restrict__ cnt1, unsigned* __restrict__ bin1,
    int* __restrict__ cnt2, unsigned* __restrict__ bin2)
{
    int bid = blockIdx.x;
    const int slice = blockIdx.x & 7;      // ~XCD id (perf heuristic only)
    if (bid < B_E1) {
        int e = bid * 256 + threadIdx.x;
        if (e < E1) {
            int s = e1s[e], d = e1d[e];
            if (s != d) {                  // remove_self_loops
                int cell = slice * NRB1 + (d >> 4);
                int pos = atomicAdd(&cnt1[cell], 1);
                if (pos < CAPC) bin1[(size_t)cell * CAPC + pos] = (unsigned)s | ((unsigned)(d & 15) << 19);
            }
        }
        return;
    }
    bid -= B_E1;
    if (bid < B_E2) {
        int e = bid * 256 + threadIdx.x;
        if (e < E2) {
            int s = e2s[e], d = e2d[e];
            if (s != d) {
                int cell = slice * NRB2 + (d >> 4);
                int pos = atomicAdd(&cnt2[cell], 1);
                if (pos < CAPC) bin2[(size_t)cell * CAPC + pos] = (unsigned)s | ((unsigned)(d & 15) << 17);
            }
        }
        return;
    }
    bid -= B_E2;
    int node = bid * 256 + threadIdx.x;
    if (node >= N0) return;
    const float4* xp = (const float4*)(x + (size_t)node * 64);

    float ss[16];
    #pragma unroll
    for (int c = 0; c < 16; ++c) ss[c] = 0.f;
    #pragma unroll
    for (int j = 0; j < 16; ++j) {
        float4 t = xp[j];
        float xk[4] = {t.x, t.y, t.z, t.w};
        #pragma unroll
        for (int kk = 0; kk < 4; ++kk)
            #pragma unroll
            for (int c = 0; c < 16; ++c)
                ss[c] = fmaf(xk[kk], W1s[(4 * j + kk) * 16 + c], ss[c]);
    }
    float a0 = 0.f, a1 = 0.f;
    #pragma unroll
    for (int c = 0; c < 8; ++c) {
        a0 = fmaf(ss[c], att1s[c], a0);
        a1 = fmaf(ss[8 + c], att1s[8 + c], a1);
    }
    unsigned* rp = rec1 + (size_t)node * 16;
    uint4 w0 = make_uint4(bf16pair(ss[0], ss[1]), bf16pair(ss[2], ss[3]),
                          bf16pair(ss[4], ss[5]), bf16pair(ss[6], ss[7]));
    uint4 w1 = make_uint4(bf16pair(ss[8], ss[9]), bf16pair(ss[10], ss[11]),
                          bf16pair(ss[12], ss[13]), bf16pair(ss[14], ss[15]));
    ((uint4*)rp)[0] = w0;
    ((uint4*)rp)[1] = w1;
    *(float2*)(rp + 8) = make_float2(a0, a1);

    if (node < N1) {                       // projD fused: reuse x row from L1
        float sd[16];
        #pragma unroll
        for (int c = 0; c < 16; ++c) sd[c] = 0.f;
        #pragma unroll
        for (int j = 0; j < 16; ++j) {
            float4 t = xp[j];
            float xk[4] = {t.x, t.y, t.z, t.w};
            #pragma unroll
            for (int kk = 0; kk < 4; ++kk)
                #pragma unroll
                for (int c = 0; c < 16; ++c)
                    sd[c] = fmaf(xk[kk], W1d[(4 * j + kk) * 16 + c], sd[c]);
        }
        float d0 = 0.f, d1 = 0.f;
        #pragma unroll
        for (int c = 0; c < 8; ++c) {
            d0 = fmaf(sd[c], att1d[c], d0);
            d1 = fmaf(sd[8 + c], att1d[8 + c], d1);
        }
        ((float2*)a_d1)[node] = make_float2(d0, d1);
    }
}

// ============ K2: layer-1 node-major aggregate (register acc) + fused proj2 ============
// rec2[node] (24 words, 96B): w0..w19 bf16x2 hs2, w20 = a_s2, w21 = a_d2
__global__ __launch_bounds__(256) void k2_kernel(
    const int* __restrict__ cnt1, const unsigned* __restrict__ bin1,
    const unsigned* __restrict__ rec1, const float* __restrict__ a_d1,
    const float* __restrict__ b1,
    const float* __restrict__ W2s, const float* __restrict__ W2d,
    const float* __restrict__ att2s, const float* __restrict__ att2d,
    unsigned* __restrict__ rec2)
{
    __shared__ unsigned raw[MAXE];
    __shared__ unsigned srt[MAXE];
    __shared__ int ns[8], csum[9];
    __shared__ int hist[16], start[17], cursor[16];
    __shared__ float w2sl[640];
    __shared__ float va[16], vd[16];
    __shared__ float h1s[16][17];
    __shared__ float as2l[16], ad2l[16];

    const int r = blockIdx.x, tid = threadIdx.x;
    const int d0 = r * 16;
    const int nN = min(16, N1 - d0);

    if (tid < 16) hist[tid] = 0;
    if (tid < 8) ns[tid] = min(cnt1[tid * NRB1 + r], CAPC);
    for (int j = tid; j < 640; j += 256) w2sl[j] = W2s[j];
    if (tid >= 32 && tid < 48) {           // va/vd: fold att2 into W2 columns
        int k = tid - 32;
        float sa = 0.f, sd = 0.f;
        for (int cc = 0; cc < 40; ++cc) {
            sa = fmaf(W2s[k * 40 + cc], att2s[cc], sa);
            sd = fmaf(W2d[k * 40 + cc], att2d[cc], sd);
        }
        va[k] = sa; vd[k] = sd;
    }
    __syncthreads();
    if (tid == 0) {
        int a = 0;
        for (int s = 0; s < 8; ++s) { csum[s] = a; a += ns[s]; }
        csum[8] = min(a, MAXE);
    }
    __syncthreads();
    for (int s = 0; s < 8; ++s) {          // copy bins to LDS + histogram by local dst
        const unsigned* bp = bin1 + (size_t)(s * NRB1 + r) * CAPC;
        int base = csum[s], n = ns[s];
        for (int i = tid; i < n; i += 256) {
            int dst = base + i;
            if (dst < MAXE) { unsigned e = bp[i]; raw[dst] = e; atomicAdd(&hist[e >> 19], 1); }
        }
    }
    __syncthreads();
    if (tid == 0) {
        int a = 0;
        for (int k = 0; k < 16; ++k) { start[k] = a; a += hist[k]; }
        start[16] = a;
    }
    __syncthreads();
    if (tid < 16) cursor[tid] = start[tid];
    __syncthreads();
    const int total = csum[8];
    for (int i = tid; i < total; i += 256) {
        unsigned e = raw[i];
        int pos = atomicAdd(&cursor[e >> 19], 1);
        srt[pos] = e & 0x7FFFFu;
    }
    __syncthreads();

    // ---- node-major aggregation: group g (16 lanes) = node d0+g, register acc ----
    const int g = tid >> 4, c = tid & 15, h = c >> 3;
    const int wbase = tid & 48;            // group base lane within wave
    const int wmap = (c < 8) ? c : (8 + ((c >> 2) & 1));
    if (g < nN) {
        const int node = d0 + g;
        const float ad = a_d1[(size_t)node * 2 + h];
        const int st = start[g], n = start[g + 1] - start[g];
        float accv = 0.f, den = 0.f;
        int scur = node;                    // self-loop first
        unsigned rw = rec1[(size_t)scur * 16 + wmap];
        for (int j = 0; j <= n; ++j) {
            int snext = (j < n) ? (int)srt[st + j] : 0;
            unsigned rwn = (j < n) ? rec1[(size_t)snext * 16 + wmap] : 0u;
            float asv = __uint_as_float((unsigned)__shfl((int)rw, wbase + 8 + 4 * h, 64));
            unsigned chw = (unsigned)__shfl((int)rw, wbase + (c >> 1), 64);
            float hv = (c & 1) ? bfHi(chw) : bfLo(chw);
            float w = __expf(leaky(asv + ad));
            accv = fmaf(w, hv, accv);
            den += w;
            rw = rwn;
        }
        float v = accv / den + b1[c];
        v = v > 0.f ? v : (__expf(v) - 1.f);   // ELU
        h1s[g][c] = v;
        float pa = v * va[c], pd = v * vd[c];
        #pragma unroll
        for (int k = 1; k < 16; k <<= 1) { pa += __shfl_xor(pa, k, 64); pd += __shfl_xor(pd, k, 64); }
        if (c == 0) { as2l[g] = pa; ad2l[g] = pd; }
    }
    __syncthreads();
    // ---- fused proj2 -> rec2 ----
    for (int i = tid; i < nN * 24; i += 256) {
        int nn = i / 24, w = i - nn * 24;
        unsigned* rp = rec2 + (size_t)(d0 + nn) * 24;
        if (w < 20) {
            int c0 = 2 * w, c1 = c0 + 1;
            float s0 = 0.f, s1 = 0.f;
            #pragma unroll
            for (int k = 0; k < 16; ++k) {
                float hk = h1s[nn][k];
                s0 = fmaf(hk, w2sl[k * 40 + c0], s0);
                s1 = fmaf(hk, w2sl[k * 40 + c1], s1);
            }
            rp[w] = bf16pair(s0, s1);
        } else if (w == 20) {
            rp[20] = __float_as_uint(as2l[nn]);
        } else if (w == 21) {
            rp[21] = __float_as_uint(ad2l[nn]);
        }
    }
}

// ============ K4: layer-2 node-major aggregate + fused log_softmax ============
__global__ __launch_bounds__(256) void k4_kernel(
    const int* __restrict__ cnt2, const unsigned* __restrict__ bin2,
    const unsigned* __restrict__ rec2, const float* __restrict__ b2,
    float* __restrict__ out)
{
    __shared__ unsigned raw[MAXE];
    __shared__ unsigned srt[MAXE];
    __shared__ int ns[8], csum[9];
    __shared__ int hist[16], start[17], cursor[16];

    const int r = blockIdx.x, tid = threadIdx.x;
    const int d0 = r * 16;
    const int nN = min(16, N2 - d0);

    if (tid < 16) hist[tid] = 0;
    if (tid < 8) ns[tid] = min(cnt2[tid * NRB2 + r], CAPC);
    __syncthreads();
    if (tid == 0) {
        int a = 0;
        for (int s = 0; s < 8; ++s) { csum[s] = a; a += ns[s]; }
        csum[8] = min(a, MAXE);
    }
    __syncthreads();
    for (int s = 0; s < 8; ++s) {
        const unsigned* bp = bin2 + (size_t)(s * NRB2 + r) * CAPC;
        int base = csum[s], n = ns[s];
        for (int i = tid; i < n; i += 256) {
            int dst = base + i;
            if (dst < MAXE) { unsigned e = bp[i]; raw[dst] = e; atomicAdd(&hist[e >> 17], 1); }
        }
    }
    __syncthreads();
    if (tid == 0) {
        int a = 0;
        for (int k = 0; k < 16; ++k) { start[k] = a; a += hist[k]; }
        start[16] = a;
    }
    __syncthreads();
    if (tid < 16) cursor[tid] = start[tid];
    __syncthreads();
    const int total = csum[8];
    for (int i = tid; i < total; i += 256) {
        unsigned e = raw[i];
        int pos = atomicAdd(&cursor[e >> 17], 1);
        srt[pos] = e & 0x1FFFFu;
    }
    __syncthreads();

    const int wv = tid >> 6, lane = tid & 63;
    const bool act = lane < NC;
    const float bb = act ? b2[lane] : 0.f;
    for (int g = wv; g < nN; g += 4) {
        const int node = d0 + g;
        const int st = start[g], n = start[g + 1] - start[g];
        int scur = node;
        unsigned rw = (lane < 22) ? rec2[(size_t)scur * 24 + lane] : 0u;
        const float ad = __uint_as_float((unsigned)__shfl((int)rw, 21, 64));
        float accv = 0.f, den = 0.f;
        for (int j = 0; j <= n; ++j) {
            int snext = (j < n) ? (int)srt[st + j] : 0;
            unsigned rwn = ((j < n) && lane < 21) ? rec2[(size_t)snext * 24 + lane] : 0u;
            float asv = __uint_as_float((unsigned)__shfl((int)rw, 20, 64));
            unsigned chw = (unsigned)__shfl((int)rw, lane >> 1, 64);
            float hv = (lane & 1) ? bfHi(chw) : bfLo(chw);
            float w = __expf(leaky(asv + ad));
            if (act) accv = fmaf(w, hv, accv);
            den += w;
            rw = rwn;
        }
        float v = act ? (accv / den + bb) : -3.4e38f;
        float vv = v;
        #pragma unroll
        for (int k = 32; k >= 1; k >>= 1) vv = fmaxf(vv, __shfl_xor(vv, k, 64));
        float ex = act ? __expf(v - vv) : 0.f;
        #pragma unroll
        for (int k = 32; k >= 1; k >>= 1) ex += __shfl_xor(ex, k, 64);
        float lse = vv + logf(ex);
        if (act) out[(size_t)node * NC + lane] = v - lse;
    }
}

extern "C" void kernel_launch(void* const* d_in, const int* in_sizes, int n_in,
                              void* d_out, int out_size, void* d_ws, size_t ws_size,
                              hipStream_t stream) {
    const float* x      = (const float*)d_in[0];
    const int*   e1_src = (const int*)d_in[1];
    const int*   e1_dst = (const int*)d_in[2];
    const int*   e2_src = (const int*)d_in[3];
    const int*   e2_dst = (const int*)d_in[4];
    const float* W1s    = (const float*)d_in[5];
    const float* W1d    = (const float*)d_in[6];
    const float* att1s  = (const float*)d_in[7];
    const float* att1d  = (const float*)d_in[8];
    const float* b1     = (const float*)d_in[9];
    const float* W2s    = (const float*)d_in[10];
    const float* W2d    = (const float*)d_in[11];
    const float* att2s  = (const float*)d_in[12];
    const float* att2d  = (const float*)d_in[13];
    const float* b2     = (const float*)d_in[14];
    float* out = (float*)d_out;

    // ---- workspace layout (4-byte words) ----
    float* wsbase = (float*)d_ws;
    size_t o = 0;
    int*      cnt1 = (int*)(wsbase + o);      o += (size_t)8 * NRB1;       // 37504
    int*      cnt2 = (int*)(wsbase + o);      o += (size_t)8 * NRB2;       //  7504
    const size_t zeroWords = o;               // only counters need zeroing
    unsigned* bin1 = (unsigned*)(wsbase + o); o += (size_t)8 * NRB1 * CAPC;
    unsigned* bin2 = (unsigned*)(wsbase + o); o += (size_t)8 * NRB2 * CAPC;
    unsigned* rec1 = (unsigned*)(wsbase + o); o += (size_t)N0 * 16;        // 64B records
    float*    a_d1 = (float*)(wsbase + o);    o += (size_t)N1 * 2;
    unsigned* rec2 = (unsigned*)(wsbase + o); o += (size_t)N1 * 24;        // 96B records

    hipMemsetAsync(d_ws, 0, zeroWords * sizeof(float), stream);

    k1_kernel<<<B_E1 + B_E2 + B_P, 256, 0, stream>>>(
        x, W1s, W1d, att1s, att1d, e1_src, e1_dst, e2_src, e2_dst,
        rec1, a_d1, cnt1, bin1, cnt2, bin2);

    k2_kernel<<<NRB1, 256, 0, stream>>>(cnt1, bin1, rec1, a_d1, b1,
                                        W2s, W2d, att2s, att2d, rec2);

    k4_kernel<<<NRB2, 256, 0, stream>>>(cnt2, bin2, rec2, b2, out);
}

// Round 6
// 179.674 us; speedup vs baseline: 1.7683x; 1.3784x over previous
//
#include <hip/hip_runtime.h>
#include <hip/hip_bf16.h>

// ---- problem constants ----
constexpr int N0 = 400000, N1 = 75000, N2 = 15000;
constexpr int E1 = 1200000, E2 = 240000;
constexpr int NC = 40;
constexpr float NEG_SLOPE = 0.2f;

// two-level binning: coarse buckets amortize global atomics over ~28-edge chunks
constexpr int BK1 = 256;                     // dst nodes per bucket, layer 1
constexpr int NB1 = (N1 + BK1 - 1) / BK1;    // 293
constexpr int CAPB1 = 4608;                  // mean 4096, sd 64 -> 8 sigma
constexpr int BK2 = 64;                      // dst nodes per bucket, layer 2
constexpr int NB2 = (N2 + BK2 - 1) / BK2;    // 235
constexpr int CAPB2 = 1536;                  // mean 1024, sd 32 -> 16 sigma

constexpr int TILE = 8192;                   // edges per binning block
constexpr int NT1 = (E1 + TILE - 1) / TILE;  // 147
constexpr int NT2 = (E2 + TILE - 1) / TILE;  // 30
constexpr int BPJ = (N0 + 511) / 512;        // 782 projection blocks

__device__ __forceinline__ float leaky(float v) { return v > 0.f ? v : NEG_SLOPE * v; }

// RNE pack of two floats into a bf16x2 word
__device__ __forceinline__ unsigned bf16pair(float lo, float hi) {
    unsigned a = __float_as_uint(lo), b = __float_as_uint(hi);
    a = (a + 0x7FFFu + ((a >> 16) & 1u)) >> 16;
    b = (b + 0x7FFFu + ((b >> 16) & 1u)) & 0xFFFF0000u;
    return a | b;
}
__device__ __forceinline__ float bfLo(unsigned w) { return __uint_as_float(w << 16); }
__device__ __forceinline__ float bfHi(unsigned w) { return __uint_as_float(w & 0xFFFF0000u); }

// ============ K1: LDS-staged binning (E1,E2) + projection ============
// rec1[node] (16 words, 64B): w0..w7 bf16x2 hs1, w8/w9 fp32 a_s (head0/1)
__global__ __launch_bounds__(512) void k1_kernel(
    const float* __restrict__ x,
    const float* __restrict__ W1s, const float* __restrict__ W1d,
    const float* __restrict__ att1s, const float* __restrict__ att1d,
    const int* __restrict__ e1s, const int* __restrict__ e1d,
    const int* __restrict__ e2s, const int* __restrict__ e2d,
    unsigned* __restrict__ rec1, float* __restrict__ a_d1,
    int* __restrict__ gcnt1, unsigned* __restrict__ bin1,
    int* __restrict__ gcnt2, unsigned* __restrict__ bin2)
{
    __shared__ int hist[NB1];      // max(NB1, NB2)
    __shared__ int gbase[NB1];

    int bid = blockIdx.x;
    if (bid < NT1 + NT2) {
        const bool isL1 = bid < NT1;
        const int* es = isL1 ? e1s : e2s;
        const int* ed = isL1 ? e1d : e2d;
        const int nE = isL1 ? E1 : E2;
        const int nb = isL1 ? NB1 : NB2;
        const int cap = isL1 ? CAPB1 : CAPB2;
        const int shift = isL1 ? 8 : 6;       // log2(BK)
        const int lsh = isL1 ? 19 : 17;       // localdst shift in payload
        int* gc = isL1 ? gcnt1 : gcnt2;
        unsigned* gbin = isL1 ? bin1 : bin2;
        const int base = (isL1 ? bid : bid - NT1) * TILE;
        const int lim = min(TILE, nE - base);

        for (int b = threadIdx.x; b < nb; b += 512) hist[b] = 0;
        __syncthreads();
        for (int i = threadIdx.x; i < lim; i += 512) {
            int s = es[base + i], d = ed[base + i];
            if (s != d) atomicAdd(&hist[d >> shift], 1);   // remove_self_loops
        }
        __syncthreads();
        for (int b = threadIdx.x; b < nb; b += 512) {
            int c = hist[b];
            gbase[b] = (c > 0) ? atomicAdd(&gc[b], c) : 0; // ONE global atomic per chunk
            hist[b] = 0;                                   // reuse as cursor
        }
        __syncthreads();
        for (int i = threadIdx.x; i < lim; i += 512) {
            int s = es[base + i], d = ed[base + i];
            if (s != d) {
                int b = d >> shift;
                int pos = gbase[b] + atomicAdd(&hist[b], 1);
                if (pos < cap)
                    gbin[(size_t)b * cap + pos] =
                        (unsigned)s | ((unsigned)(d & ((1 << shift) - 1)) << lsh);
            }
        }
        return;
    }
    // ---- projection: one node per thread ----
    int node = (bid - NT1 - NT2) * 512 + threadIdx.x;
    if (node >= N0) return;
    const float4* xp = (const float4*)(x + (size_t)node * 64);

    float ss[16];
    #pragma unroll
    for (int c = 0; c < 16; ++c) ss[c] = 0.f;
    #pragma unroll
    for (int j = 0; j < 16; ++j) {
        float4 t = xp[j];
        float xk[4] = {t.x, t.y, t.z, t.w};
        #pragma unroll
        for (int kk = 0; kk < 4; ++kk)
            #pragma unroll
            for (int c = 0; c < 16; ++c)
                ss[c] = fmaf(xk[kk], W1s[(4 * j + kk) * 16 + c], ss[c]);
    }
    float a0 = 0.f, a1 = 0.f;
    #pragma unroll
    for (int c = 0; c < 8; ++c) {
        a0 = fmaf(ss[c], att1s[c], a0);
        a1 = fmaf(ss[8 + c], att1s[8 + c], a1);
    }
    unsigned* rp = rec1 + (size_t)node * 16;
    ((uint4*)rp)[0] = make_uint4(bf16pair(ss[0], ss[1]), bf16pair(ss[2], ss[3]),
                                 bf16pair(ss[4], ss[5]), bf16pair(ss[6], ss[7]));
    ((uint4*)rp)[1] = make_uint4(bf16pair(ss[8], ss[9]), bf16pair(ss[10], ss[11]),
                                 bf16pair(ss[12], ss[13]), bf16pair(ss[14], ss[15]));
    *(float2*)(rp + 8) = make_float2(a0, a1);

    if (node < N1) {                          // projD fused (x row L2-hot)
        float sd[16];
        #pragma unroll
        for (int c = 0; c < 16; ++c) sd[c] = 0.f;
        #pragma unroll
        for (int j = 0; j < 16; ++j) {
            float4 t = xp[j];
            float xk[4] = {t.x, t.y, t.z, t.w};
            #pragma unroll
            for (int kk = 0; kk < 4; ++kk)
                #pragma unroll
                for (int c = 0; c < 16; ++c)
                    sd[c] = fmaf(xk[kk], W1d[(4 * j + kk) * 16 + c], sd[c]);
        }
        float d0 = 0.f, d1 = 0.f;
        #pragma unroll
        for (int c = 0; c < 8; ++c) {
            d0 = fmaf(sd[c], att1d[c], d0);
            d1 = fmaf(sd[8 + c], att1d[8 + c], d1);
        }
        ((float2*)a_d1)[node] = make_float2(d0, d1);
    }
}

// ============ K2: layer-1 bucket sort + node-major aggregate + fused proj2 ============
// rec2[node] (24 words, 96B): w0..w19 bf16x2 hs2, w20 a_s2, w21 a_d2
__global__ __launch_bounds__(1024) void k2_kernel(
    const int* __restrict__ gcnt1, const unsigned* __restrict__ bin1,
    const unsigned* __restrict__ rec1, const float* __restrict__ a_d1,
    const float* __restrict__ b1,
    const float* __restrict__ W2s, const float* __restrict__ W2d,
    const float* __restrict__ att2s, const float* __restrict__ att2d,
    unsigned* __restrict__ rec2)
{
    __shared__ unsigned srt[CAPB1];
    __shared__ int hist[BK1], start[BK1 + 1];
    __shared__ float w2sl[640], va[16], vd[16];
    __shared__ float h1s[BK1][17];

    const int b = blockIdx.x, tid = threadIdx.x;
    const int d0 = b * BK1;
    const int nN = min(BK1, N1 - d0);
    const int ncnt = min(gcnt1[b], CAPB1);
    const unsigned* bp = bin1 + (size_t)b * CAPB1;

    for (int i = tid; i < 640; i += 1024) w2sl[i] = W2s[i];
    if (tid < BK1) hist[tid] = 0;
    if (tid >= 256 && tid < 272) {            // fold att2 into W2 columns
        int k = tid - 256;
        float sa = 0.f, sd = 0.f;
        for (int cc = 0; cc < 40; ++cc) {
            sa = fmaf(W2s[k * 40 + cc], att2s[cc], sa);
            sd = fmaf(W2d[k * 40 + cc], att2d[cc], sd);
        }
        va[k] = sa; vd[k] = sd;
    }
    __syncthreads();
    for (int i = tid; i < ncnt; i += 1024) atomicAdd(&hist[bp[i] >> 19], 1);
    __syncthreads();
    if (tid == 0) {
        int a = 0;
        for (int k = 0; k < BK1; ++k) { start[k] = a; a += hist[k]; }
        start[BK1] = a;
    }
    __syncthreads();
    if (tid < BK1) hist[tid] = start[tid];    // cursor
    __syncthreads();
    for (int i = tid; i < ncnt; i += 1024) {
        unsigned p = bp[i];
        int pos = atomicAdd(&hist[p >> 19], 1);
        srt[pos] = p & 0x7FFFFu;
    }
    __syncthreads();

    // node-major aggregation: 64 groups of 16 lanes, 2-deep prefetch
    const int g = tid >> 4, c = tid & 15, h = c >> 3;
    const int wbase = tid & 48;
    const int wmap = (c < 8) ? c : (8 + ((c >> 2) & 1));
    for (int n = g; n < nN; n += 64) {
        const int node = d0 + n;
        const float ad = a_d1[(size_t)node * 2 + h];
        const int st = start[n], cnt = start[n + 1] - start[n];
        unsigned rwA = rec1[(size_t)node * 16 + wmap];                       // self
        unsigned rwB = (cnt > 0) ? rec1[(size_t)srt[st] * 16 + wmap] : 0u;
        float accv = 0.f, den = 0.f;
        for (int j = 0; j <= cnt; ++j) {
            unsigned rwC = (j + 2 <= cnt) ? rec1[(size_t)srt[st + j + 1] * 16 + wmap] : 0u;
            float asv = __uint_as_float((unsigned)__shfl((int)rwA, wbase + 8 + 4 * h, 64));
            unsigned chw = (unsigned)__shfl((int)rwA, wbase + (c >> 1), 64);
            float hv = (c & 1) ? bfHi(chw) : bfLo(chw);
            float w = __expf(leaky(asv + ad));
            accv = fmaf(w, hv, accv);
            den += w;
            rwA = rwB; rwB = rwC;
        }
        float v = accv / den + b1[c];
        h1s[n][c] = v > 0.f ? v : (__expf(v) - 1.f);    // ELU
    }
    __syncthreads();
    // fused proj2 -> rec2
    for (int i = tid; i < nN * 24; i += 1024) {
        int nn = i / 24, w = i - nn * 24;
        unsigned* rp = rec2 + (size_t)(d0 + nn) * 24;
        if (w < 20) {
            int c0 = 2 * w, c1 = c0 + 1;
            float s0 = 0.f, s1 = 0.f;
            #pragma unroll
            for (int k = 0; k < 16; ++k) {
                float hk = h1s[nn][k];
                s0 = fmaf(hk, w2sl[k * 40 + c0], s0);
                s1 = fmaf(hk, w2sl[k * 40 + c1], s1);
            }
            rp[w] = bf16pair(s0, s1);
        } else if (w < 22) {
            const float* vv = (w == 20) ? va : vd;
            float s = 0.f;
            #pragma unroll
            for (int k = 0; k < 16; ++k) s = fmaf(h1s[nn][k], vv[k], s);
            rp[w] = __float_as_uint(s);
        }
    }
}

// ============ K3: layer-2 bucket sort + 32-lane-group aggregate + log_softmax ============
__global__ __launch_bounds__(1024) void k3_kernel(
    const int* __restrict__ gcnt2, const unsigned* __restrict__ bin2,
    const unsigned* __restrict__ rec2, const float* __restrict__ b2,
    float* __restrict__ out)
{
    __shared__ unsigned srt[CAPB2];
    __shared__ int hist[BK2], start[BK2 + 1];

    const int b = blockIdx.x, tid = threadIdx.x;
    const int d0 = b * BK2;
    const int nN = min(BK2, N2 - d0);
    const int ncnt = min(gcnt2[b], CAPB2);
    const unsigned* bp = bin2 + (size_t)b * CAPB2;

    if (tid < BK2) hist[tid] = 0;
    __syncthreads();
    for (int i = tid; i < ncnt; i += 1024) atomicAdd(&hist[bp[i] >> 17], 1);
    __syncthreads();
    if (tid == 0) {
        int a = 0;
        for (int k = 0; k < BK2; ++k) { start[k] = a; a += hist[k]; }
        start[BK2] = a;
    }
    __syncthreads();
    if (tid < BK2) hist[tid] = start[tid];
    __syncthreads();
    for (int i = tid; i < ncnt; i += 1024) {
        unsigned p = bp[i];
        int pos = atomicAdd(&hist[p >> 17], 1);
        srt[pos] = p & 0x1FFFFu;
    }
    __syncthreads();

    // 32 groups of 32 lanes; lane l holds record word l (channels 2l, 2l+1 for l<20)
    const int g = tid >> 5, l = tid & 31;
    const float bb0 = (l < 20) ? b2[2 * l] : 0.f;
    const float bb1 = (l < 20) ? b2[2 * l + 1] : 0.f;
    for (int n = g; n < nN; n += 32) {
        const int node = d0 + n;
        const int st = start[n], cnt = start[n + 1] - start[n];
        unsigned rwA = (l < 22) ? rec2[(size_t)node * 24 + l] : 0u;          // self
        const float ad = __uint_as_float((unsigned)__shfl((int)rwA, 21, 32));
        unsigned rwB = (cnt > 0 && l < 21) ? rec2[(size_t)srt[st] * 24 + l] : 0u;
        float a0 = 0.f, a1 = 0.f, den = 0.f;
        for (int j = 0; j <= cnt; ++j) {
            unsigned rwC = (j + 2 <= cnt && l < 21) ? rec2[(size_t)srt[st + j + 1] * 24 + l] : 0u;
            float asv = __uint_as_float((unsigned)__shfl((int)rwA, 20, 32));
            float w = __expf(leaky(asv + ad));
            a0 = fmaf(w, bfLo(rwA), a0);
            a1 = fmaf(w, bfHi(rwA), a1);
            den += w;
            rwA = rwB; rwB = rwC;
        }
        float v0 = (l < 20) ? a0 / den + bb0 : -3.4e38f;
        float v1 = (l < 20) ? a1 / den + bb1 : -3.4e38f;
        float mx = fmaxf(v0, v1);
        #pragma unroll
        for (int k = 16; k >= 1; k >>= 1) mx = fmaxf(mx, __shfl_xor(mx, k, 32));
        float ex = (l < 20) ? __expf(v0 - mx) + __expf(v1 - mx) : 0.f;
        #pragma unroll
        for (int k = 16; k >= 1; k >>= 1) ex += __shfl_xor(ex, k, 32);
        float lse = mx + logf(ex);
        if (l < 20)
            ((float2*)(out + (size_t)node * 40))[l] = make_float2(v0 - lse, v1 - lse);
    }
}

extern "C" void kernel_launch(void* const* d_in, const int* in_sizes, int n_in,
                              void* d_out, int out_size, void* d_ws, size_t ws_size,
                              hipStream_t stream) {
    const float* x      = (const float*)d_in[0];
    const int*   e1_src = (const int*)d_in[1];
    const int*   e1_dst = (const int*)d_in[2];
    const int*   e2_src = (const int*)d_in[3];
    const int*   e2_dst = (const int*)d_in[4];
    const float* W1s    = (const float*)d_in[5];
    const float* W1d    = (const float*)d_in[6];
    const float* att1s  = (const float*)d_in[7];
    const float* att1d  = (const float*)d_in[8];
    const float* b1     = (const float*)d_in[9];
    const float* W2s    = (const float*)d_in[10];
    const float* W2d    = (const float*)d_in[11];
    const float* att2s  = (const float*)d_in[12];
    const float* att2d  = (const float*)d_in[13];
    const float* b2     = (const float*)d_in[14];
    float* out = (float*)d_out;

    // ---- workspace layout (4-byte words) ----
    float* wsbase = (float*)d_ws;
    size_t o = 0;
    int*      gcnt1 = (int*)(wsbase + o);     o += NB1;
    int*      gcnt2 = (int*)(wsbase + o);     o += NB2;
    const size_t zeroWords = o;               // only counters need zeroing
    unsigned* bin1  = (unsigned*)(wsbase + o); o += (size_t)NB1 * CAPB1;
    unsigned* bin2  = (unsigned*)(wsbase + o); o += (size_t)NB2 * CAPB2;
    unsigned* rec1  = (unsigned*)(wsbase + o); o += (size_t)N0 * 16;
    float*    a_d1  = (float*)(wsbase + o);    o += (size_t)N1 * 2;
    unsigned* rec2  = (unsigned*)(wsbase + o); o += (size_t)N1 * 24;

    hipMemsetAsync(d_ws, 0, zeroWords * sizeof(float), stream);

    k1_kernel<<<NT1 + NT2 + BPJ, 512, 0, stream>>>(
        x, W1s, W1d, att1s, att1d, e1_src, e1_dst, e2_src, e2_dst,
        rec1, a_d1, gcnt1, bin1, gcnt2, bin2);

    k2_kernel<<<NB1, 1024, 0, stream>>>(gcnt1, bin1, rec1, a_d1, b1,
                                        W2s, W2d, att2s, att2d, rec2);

    k3_kernel<<<NB2, 1024, 0, stream>>>(gcnt2, bin2, rec2, b2, out);
}

// Round 7
// 139.974 us; speedup vs baseline: 2.2698x; 1.2836x over previous
//
#include <hip/hip_runtime.h>
#include <hip/hip_bf16.h>

// ---- problem constants ----
constexpr int N0 = 400000, N1 = 75000, N2 = 15000;
constexpr int E1 = 1200000, E2 = 240000;
constexpr int NC = 40;
constexpr float NEG_SLOPE = 0.2f;

// two-level binning: coarse buckets amortize global atomics over edge chunks
constexpr int BK1 = 128;                     // dst nodes per bucket, layer 1
constexpr int NB1 = (N1 + BK1 - 1) / BK1;    // 586
constexpr int CAPB1 = 2432;                  // mean 2048, sd ~45 -> +8.5 sigma
constexpr int BK2 = 32;                      // dst nodes per bucket, layer 2
constexpr int NB2 = (N2 + BK2 - 1) / BK2;    // 469
constexpr int CAPB2 = 704;                   // mean 512, sd ~23 -> +8.5 sigma

constexpr int TILE = 8192;                   // edges per binning block
constexpr int NT1 = (E1 + TILE - 1) / TILE;  // 147
constexpr int NT2 = (E2 + TILE - 1) / TILE;  // 30
constexpr int BPJ = (N0 + 511) / 512;        // 782 projection blocks

__device__ __forceinline__ float leaky(float v) { return v > 0.f ? v : NEG_SLOPE * v; }

// RNE pack of two floats into a bf16x2 word
__device__ __forceinline__ unsigned bf16pair(float lo, float hi) {
    unsigned a = __float_as_uint(lo), b = __float_as_uint(hi);
    a = (a + 0x7FFFu + ((a >> 16) & 1u)) >> 16;
    b = (b + 0x7FFFu + ((b >> 16) & 1u)) & 0xFFFF0000u;
    return a | b;
}
__device__ __forceinline__ float bfLo(unsigned w) { return __uint_as_float(w << 16); }
__device__ __forceinline__ float bfHi(unsigned w) { return __uint_as_float(w & 0xFFFF0000u); }

// ============ K1: projection (full-row register load) + LDS-staged binning ============
// rec1[node] (16 words, 64B): w0..w7 bf16x2 hs1, w8/w9 fp32 a_s; w10..15 pad (full-line store)
__global__ __launch_bounds__(512, 4) void k1_kernel(
    const float* __restrict__ x,
    const float* __restrict__ W1s, const float* __restrict__ W1d,
    const float* __restrict__ att1s, const float* __restrict__ att1d,
    const int* __restrict__ e1s, const int* __restrict__ e1d,
    const int* __restrict__ e2s, const int* __restrict__ e2d,
    unsigned* __restrict__ rec1, float* __restrict__ a_d1,
    int* __restrict__ gcnt1, unsigned* __restrict__ bin1,
    int* __restrict__ gcnt2, unsigned* __restrict__ bin2)
{
    __shared__ int hist[NB1];      // NB1 >= NB2
    __shared__ int gbase[NB1];

    int bid = blockIdx.x;
    if (bid < BPJ) {
        // ---- projection: one node per thread, x row resident in 16 float4 regs ----
        int node = bid * 512 + threadIdx.x;
        if (node >= N0) return;
        const float4* xp = (const float4*)(x + (size_t)node * 64);
        float4 xr[16];
        #pragma unroll
        for (int j = 0; j < 16; ++j) xr[j] = xp[j];      // deep MLP: 16 loads in flight

        float ss[16];
        #pragma unroll
        for (int c = 0; c < 16; ++c) ss[c] = 0.f;
        #pragma unroll
        for (int j = 0; j < 16; ++j) {
            float xk[4] = {xr[j].x, xr[j].y, xr[j].z, xr[j].w};
            #pragma unroll
            for (int kk = 0; kk < 4; ++kk)
                #pragma unroll
                for (int c = 0; c < 16; ++c)
                    ss[c] = fmaf(xk[kk], W1s[(4 * j + kk) * 16 + c], ss[c]);
        }
        float a0 = 0.f, a1 = 0.f;
        #pragma unroll
        for (int c = 0; c < 8; ++c) {
            a0 = fmaf(ss[c], att1s[c], a0);
            a1 = fmaf(ss[8 + c], att1s[8 + c], a1);
        }
        unsigned* rp = rec1 + (size_t)node * 16;
        ((uint4*)rp)[0] = make_uint4(bf16pair(ss[0], ss[1]), bf16pair(ss[2], ss[3]),
                                     bf16pair(ss[4], ss[5]), bf16pair(ss[6], ss[7]));
        ((uint4*)rp)[1] = make_uint4(bf16pair(ss[8], ss[9]), bf16pair(ss[10], ss[11]),
                                     bf16pair(ss[12], ss[13]), bf16pair(ss[14], ss[15]));
        ((uint4*)rp)[2] = make_uint4(__float_as_uint(a0), __float_as_uint(a1), 0u, 0u);
        ((uint4*)rp)[3] = make_uint4(0u, 0u, 0u, 0u);    // full 64B line: no RFO

        if (node < N1) {                       // projD from registers (no re-read)
            float sd[16];
            #pragma unroll
            for (int c = 0; c < 16; ++c) sd[c] = 0.f;
            #pragma unroll
            for (int j = 0; j < 16; ++j) {
                float xk[4] = {xr[j].x, xr[j].y, xr[j].z, xr[j].w};
                #pragma unroll
                for (int kk = 0; kk < 4; ++kk)
                    #pragma unroll
                    for (int c = 0; c < 16; ++c)
                        sd[c] = fmaf(xk[kk], W1d[(4 * j + kk) * 16 + c], sd[c]);
            }
            float d0 = 0.f, d1 = 0.f;
            #pragma unroll
            for (int c = 0; c < 8; ++c) {
                d0 = fmaf(sd[c], att1d[c], d0);
                d1 = fmaf(sd[8 + c], att1d[8 + c], d1);
            }
            ((float2*)a_d1)[node] = make_float2(d0, d1);
        }
        return;
    }
    // ---- binning tiles ----
    bid -= BPJ;
    const bool isL1 = bid < NT1;
    const int* es = isL1 ? e1s : e2s;
    const int* ed = isL1 ? e1d : e2d;
    const int nE = isL1 ? E1 : E2;
    const int nb = isL1 ? NB1 : NB2;
    const int cap = isL1 ? CAPB1 : CAPB2;
    const int shift = isL1 ? 7 : 5;           // log2(BK)
    const int lsh = isL1 ? 19 : 17;           // local-dst shift in payload
    int* gc = isL1 ? gcnt1 : gcnt2;
    unsigned* gbin = isL1 ? bin1 : bin2;
    const int base = (isL1 ? bid : bid - NT1) * TILE;
    const int lim = min(TILE, nE - base);

    for (int b = threadIdx.x; b < nb; b += 512) hist[b] = 0;
    __syncthreads();
    for (int i = threadIdx.x; i < lim; i += 512) {
        int s = es[base + i], d = ed[base + i];
        if (s != d) atomicAdd(&hist[d >> shift], 1);   // remove_self_loops
    }
    __syncthreads();
    for (int b = threadIdx.x; b < nb; b += 512) {
        int c = hist[b];
        gbase[b] = (c > 0) ? atomicAdd(&gc[b], c) : 0; // ONE global atomic per chunk
        hist[b] = 0;                                   // reuse as cursor
    }
    __syncthreads();
    for (int i = threadIdx.x; i < lim; i += 512) {
        int s = es[base + i], d = ed[base + i];
        if (s != d) {
            int b = d >> shift;
            int pos = gbase[b] + atomicAdd(&hist[b], 1);
            if (pos < cap)
                gbin[(size_t)b * cap + pos] =
                    (unsigned)s | ((unsigned)(d & ((1 << shift) - 1)) << lsh);
        }
    }
}

// ============ K2: layer-1 bucket sort + node-major aggregate + fused proj2 ============
// rec2[node] (24 words, 96B): w0..w19 bf16x2 hs2, w20 a_s2, w21 a_d2
__global__ __launch_bounds__(512) void k2_kernel(
    const int* __restrict__ gcnt1, const unsigned* __restrict__ bin1,
    const unsigned* __restrict__ rec1, const float* __restrict__ a_d1,
    const float* __restrict__ b1,
    const float* __restrict__ W2s, const float* __restrict__ W2d,
    const float* __restrict__ att2s, const float* __restrict__ att2d,
    unsigned* __restrict__ rec2)
{
    __shared__ unsigned srt[CAPB1];
    __shared__ int hist[BK1], start[BK1 + 1];
    __shared__ float w2sl[640], va[16], vd[16];
    __shared__ float h1s[BK1][17];

    const int b = blockIdx.x, tid = threadIdx.x;
    const int d0 = b * BK1;
    const int nN = min(BK1, N1 - d0);
    const int ncnt = min(gcnt1[b], CAPB1);
    const unsigned* bp = bin1 + (size_t)b * CAPB1;

    for (int i = tid; i < 640; i += 512) w2sl[i] = W2s[i];
    if (tid < BK1) hist[tid] = 0;
    if (tid >= 128 && tid < 144) {            // fold att2 into W2 columns
        int k = tid - 128;
        float sa = 0.f, sd = 0.f;
        for (int cc = 0; cc < 40; ++cc) {
            sa = fmaf(W2s[k * 40 + cc], att2s[cc], sa);
            sd = fmaf(W2d[k * 40 + cc], att2d[cc], sd);
        }
        va[k] = sa; vd[k] = sd;
    }
    __syncthreads();
    for (int i = tid; i < ncnt; i += 512) atomicAdd(&hist[bp[i] >> 19], 1);
    __syncthreads();
    if (tid == 0) {
        int a = 0;
        for (int k = 0; k < BK1; ++k) { start[k] = a; a += hist[k]; }
        start[BK1] = a;
    }
    __syncthreads();
    if (tid < BK1) hist[tid] = start[tid];    // cursor
    __syncthreads();
    for (int i = tid; i < ncnt; i += 512) {
        unsigned p = bp[i];
        int pos = atomicAdd(&hist[p >> 19], 1);
        srt[pos] = p & 0x7FFFFu;
    }
    __syncthreads();

    // node-major aggregation: 32 groups of 16 lanes, 2-deep prefetch
    const int g = tid >> 4, c = tid & 15, h = c >> 3;
    const int wbase = tid & 48;
    const int wmap = (c < 8) ? c : (8 + ((c >> 2) & 1));
    for (int n = g; n < nN; n += 32) {
        const int node = d0 + n;
        const float ad = a_d1[(size_t)node * 2 + h];
        const int st = start[n], cnt = start[n + 1] - start[n];
        unsigned rwA = rec1[(size_t)node * 16 + wmap];                       // self
        unsigned rwB = (cnt > 0) ? rec1[(size_t)srt[st] * 16 + wmap] : 0u;
        float accv = 0.f, den = 0.f;
        for (int j = 0; j <= cnt; ++j) {
            unsigned rwC = (j + 2 <= cnt) ? rec1[(size_t)srt[st + j + 1] * 16 + wmap] : 0u;
            float asv = __uint_as_float((unsigned)__shfl((int)rwA, wbase + 8 + 4 * h, 64));
            unsigned chw = (unsigned)__shfl((int)rwA, wbase + (c >> 1), 64);
            float hv = (c & 1) ? bfHi(chw) : bfLo(chw);
            float w = __expf(leaky(asv + ad));
            accv = fmaf(w, hv, accv);
            den += w;
            rwA = rwB; rwB = rwC;
        }
        float v = accv / den + b1[c];
        h1s[n][c] = v > 0.f ? v : (__expf(v) - 1.f);    // ELU
    }
    __syncthreads();
    // fused proj2 -> rec2
    for (int i = tid; i < nN * 24; i += 512) {
        int nn = i / 24, w = i - nn * 24;
        unsigned* rp = rec2 + (size_t)(d0 + nn) * 24;
        if (w < 20) {
            int c0 = 2 * w, c1 = c0 + 1;
            float s0 = 0.f, s1 = 0.f;
            #pragma unroll
            for (int k = 0; k < 16; ++k) {
                float hk = h1s[nn][k];
                s0 = fmaf(hk, w2sl[k * 40 + c0], s0);
                s1 = fmaf(hk, w2sl[k * 40 + c1], s1);
            }
            rp[w] = bf16pair(s0, s1);
        } else if (w < 22) {
            const float* vv = (w == 20) ? va : vd;
            float s = 0.f;
            #pragma unroll
            for (int k = 0; k < 16; ++k) s = fmaf(h1s[nn][k], vv[k], s);
            rp[w] = __float_as_uint(s);
        }
    }
}

// ============ K3: layer-2 bucket sort + 32-lane-group aggregate + log_softmax ============
__global__ __launch_bounds__(1024) void k3_kernel(
    const int* __restrict__ gcnt2, const unsigned* __restrict__ bin2,
    const unsigned* __restrict__ rec2, const float* __restrict__ b2,
    float* __restrict__ out)
{
    __shared__ unsigned srt[CAPB2];
    __shared__ int hist[BK2], start[BK2 + 1];

    const int b = blockIdx.x, tid = threadIdx.x;
    const int d0 = b * BK2;
    const int nN = min(BK2, N2 - d0);
    const int ncnt = min(gcnt2[b], CAPB2);
    const unsigned* bp = bin2 + (size_t)b * CAPB2;

    if (tid < BK2) hist[tid] = 0;
    __syncthreads();
    for (int i = tid; i < ncnt; i += 1024) atomicAdd(&hist[bp[i] >> 17], 1);
    __syncthreads();
    if (tid == 0) {
        int a = 0;
        for (int k = 0; k < BK2; ++k) { start[k] = a; a += hist[k]; }
        start[BK2] = a;
    }
    __syncthreads();
    if (tid < BK2) hist[tid] = start[tid];
    __syncthreads();
    for (int i = tid; i < ncnt; i += 1024) {
        unsigned p = bp[i];
        int pos = atomicAdd(&hist[p >> 17], 1);
        srt[pos] = p & 0x1FFFFu;
    }
    __syncthreads();

    // 32 groups of 32 lanes; lane l holds record word l (channels 2l,2l+1 for l<20)
    const int g = tid >> 5, l = tid & 31;
    const float bb0 = (l < 20) ? b2[2 * l] : 0.f;
    const float bb1 = (l < 20) ? b2[2 * l + 1] : 0.f;
    for (int n = g; n < nN; n += 32) {
        const int node = d0 + n;
        const int st = start[n], cnt = start[n + 1] - start[n];
        unsigned rwA = (l < 22) ? rec2[(size_t)node * 24 + l] : 0u;          // self
        const float ad = __uint_as_float((unsigned)__shfl((int)rwA, 21, 32));
        unsigned rwB = (cnt > 0 && l < 21) ? rec2[(size_t)srt[st] * 24 + l] : 0u;
        float a0 = 0.f, a1 = 0.f, den = 0.f;
        for (int j = 0; j <= cnt; ++j) {
            unsigned rwC = (j + 2 <= cnt && l < 21) ? rec2[(size_t)srt[st + j + 1] * 24 + l] : 0u;
            float asv = __uint_as_float((unsigned)__shfl((int)rwA, 20, 32));
            float w = __expf(leaky(asv + ad));
            a0 = fmaf(w, bfLo(rwA), a0);
            a1 = fmaf(w, bfHi(rwA), a1);
            den += w;
            rwA = rwB; rwB = rwC;
        }
        float v0 = (l < 20) ? a0 / den + bb0 : -3.4e38f;
        float v1 = (l < 20) ? a1 / den + bb1 : -3.4e38f;
        float mx = fmaxf(v0, v1);
        #pragma unroll
        for (int k = 16; k >= 1; k >>= 1) mx = fmaxf(mx, __shfl_xor(mx, k, 32));
        float ex = (l < 20) ? __expf(v0 - mx) + __expf(v1 - mx) : 0.f;
        #pragma unroll
        for (int k = 16; k >= 1; k >>= 1) ex += __shfl_xor(ex, k, 32);
        float lse = mx + logf(ex);
        if (l < 20)
            ((float2*)(out + (size_t)node * 40))[l] = make_float2(v0 - lse, v1 - lse);
    }
}

extern "C" void kernel_launch(void* const* d_in, const int* in_sizes, int n_in,
                              void* d_out, int out_size, void* d_ws, size_t ws_size,
                              hipStream_t stream) {
    const float* x      = (const float*)d_in[0];
    const int*   e1_src = (const int*)d_in[1];
    const int*   e1_dst = (const int*)d_in[2];
    const int*   e2_src = (const int*)d_in[3];
    const int*   e2_dst = (const int*)d_in[4];
    const float* W1s    = (const float*)d_in[5];
    const float* W1d    = (const float*)d_in[6];
    const float* att1s  = (const float*)d_in[7];
    const float* att1d  = (const float*)d_in[8];
    const float* b1     = (const float*)d_in[9];
    const float* W2s    = (const float*)d_in[10];
    const float* W2d    = (const float*)d_in[11];
    const float* att2s  = (const float*)d_in[12];
    const float* att2d  = (const float*)d_in[13];
    const float* b2     = (const float*)d_in[14];
    float* out = (float*)d_out;

    // ---- workspace layout (4-byte words) ----
    float* wsbase = (float*)d_ws;
    size_t o = 0;
    int*      gcnt1 = (int*)(wsbase + o);      o += NB1;
    int*      gcnt2 = (int*)(wsbase + o);      o += NB2;
    const size_t zeroWords = o;                // only counters need zeroing
    unsigned* bin1  = (unsigned*)(wsbase + o); o += (size_t)NB1 * CAPB1;
    unsigned* bin2  = (unsigned*)(wsbase + o); o += (size_t)NB2 * CAPB2;
    unsigned* rec1  = (unsigned*)(wsbase + o); o += (size_t)N0 * 16;
    float*    a_d1  = (float*)(wsbase + o);    o += (size_t)N1 * 2;
    unsigned* rec2  = (unsigned*)(wsbase + o); o += (size_t)N1 * 24;

    hipMemsetAsync(d_ws, 0, zeroWords * sizeof(float), stream);

    k1_kernel<<<BPJ + NT1 + NT2, 512, 0, stream>>>(
        x, W1s, W1d, att1s, att1d, e1_src, e1_dst, e2_src, e2_dst,
        rec1, a_d1, gcnt1, bin1, gcnt2, bin2);

    k2_kernel<<<NB1, 512, 0, stream>>>(gcnt1, bin1, rec1, a_d1, b1,
                                       W2s, W2d, att2s, att2d, rec2);

    k3_kernel<<<NB2, 1024, 0, stream>>>(gcnt2, bin2, rec2, b2, out);
}